// Round 5
// baseline (307.717 us; speedup 1.0000x reference)
//
#include <hip/hip_runtime.h>

#define B_ 512
#define L_ 512
#define N_ 128
#define TM 256          // boundary: fwd produces alpha_255, bwd produces beta_255
#define C_BIAS 3.0f

typedef _Float16 h2_t __attribute__((ext_vector_type(2)));
typedef _Float16 h8_t __attribute__((ext_vector_type(8)));
typedef float    f4_t __attribute__((ext_vector_type(4)));

// ---- full-rate VALU wave-64 reductions via DPP (no ds_swizzle chains) ----
#define DPP_STEP_MAX(v, ctrl)                                                   \
    {                                                                           \
        int _t = __builtin_amdgcn_update_dpp(__float_as_int(v),                 \
                    __float_as_int(v), ctrl, 0xf, 0xf, false);                  \
        v = fmaxf(v, __int_as_float(_t));                                       \
    }
#define DPP_STEP_ADD(v, ctrl)                                                   \
    {                                                                           \
        int _t = __builtin_amdgcn_update_dpp(__float_as_int(v),                 \
                    __float_as_int(v), ctrl, 0xf, 0xf, false);                  \
        v = v + __int_as_float(_t);                                             \
    }

__device__ __forceinline__ float wave_max(float v) {
    DPP_STEP_MAX(v, 0xB1);   // quad_perm [1,0,3,2]
    DPP_STEP_MAX(v, 0x4E);   // quad_perm [2,3,0,1]
    DPP_STEP_MAX(v, 0x141);  // row_half_mirror
    DPP_STEP_MAX(v, 0x140);  // row_mirror
    DPP_STEP_MAX(v, 0x142);  // row_bcast15
    DPP_STEP_MAX(v, 0x143);  // row_bcast31
    return __int_as_float(__builtin_amdgcn_readlane(__float_as_int(v), 63));
}
__device__ __forceinline__ float wave_sum(float v) {
    DPP_STEP_ADD(v, 0xB1);
    DPP_STEP_ADD(v, 0x4E);
    DPP_STEP_ADD(v, 0x141);
    DPP_STEP_ADD(v, 0x140);
    DPP_STEP_ADD(v, 0x142);  // lane63 path stays exact; other lanes don't matter
    DPP_STEP_ADD(v, 0x143);
    return __int_as_float(__builtin_amdgcn_readlane(__float_as_int(v), 63));
}

// One j-tile chain: 4 MFMAs over the K slices, ks ascending (same accumulation
// order as R3 → bit-identical results). Intrinsics only: compiler handles all
// MFMA hazards (the R4 hand-asm broke exactly there).
#define CHAIN4(qv, BT)                                                          \
    f4_t qv = __builtin_amdgcn_mfma_f32_16x16x32_f16(A0, BT[0], z, 0, 0, 0);    \
    qv = __builtin_amdgcn_mfma_f32_16x16x32_f16(A1, BT[1], qv, 0, 0, 0);        \
    qv = __builtin_amdgcn_mfma_f32_16x16x32_f16(A2, BT[2], qv, 0, 0, 0);        \
    qv = __builtin_amdgcn_mfma_f32_16x16x32_f16(A3, BT[3], qv, 0, 0, 0);

// ---------------------------------------------------------------------------
// norm_kernel: 1024 blocks x 64 threads (1 wave) = 1 wave/SIMD. Barrier-free,
// wave-synchronous. Per step the 128-wide LSE matvec runs on the MATRIX pipe:
//   S[16*jt + (l&15)] = sum_i E[i] * eT[i][j]  via 8 j-tiles x 4 K-slices of
//   v_mfma_f32_16x16x32_f16; A = E broadcast-replicated over 16 rows (4x
//   ds_read_b128 row-uniform), B = static exp(trans) fragments (launch_bounds
//   (64,1): full register budget, no AGPR copy traffic).
// A-rows replicated => EVERY lane holds S[16jt + (l&15)] for all jt in regs.
// State ownership matches that layout: lane l owns s0 = 32*(l>>4) + (l&15)
// and s1 = s0 + 16 (jt = 2h, 2h+1) — the per-lane pickup is a 3-deep cndmask
// tree, NO LDS round-trip (R3's Sl scatter/gather was ~100+ cy of the serial
// critical path). Numerics identical to R3 (same per-state MFMA chain order).
// ---------------------------------------------------------------------------
__global__ __launch_bounds__(64, 1) void norm_kernel(
    const float* __restrict__ em, const int* __restrict__ tg,
    const float* __restrict__ mask, const float* __restrict__ st,
    const float* __restrict__ trans,
    float* __restrict__ alpha, float* __restrict__ beta,
    float* __restrict__ pathf, float* __restrict__ pathb)
{
    __shared__ __align__(16) _Float16 Eh[128];   // broadcast E/F vector (f16)
    __shared__ float Mlds[TM];                   // mask row half

    const int l  = threadIdx.x;
    const int c  = l & 15;       // MFMA n-index (D col)
    const int h  = l >> 4;       // MFMA k-group
    const int s0 = 32 * h + c;   // owned state 0  (j-tile 2h)
    const int s1 = s0 + 16;      // owned state 1  (j-tile 2h+1)
    const bool hb0 = (h & 1) != 0;
    const bool hb1 = (h & 2) != 0;
    const int b  = blockIdx.x >> 1;
    const int bw = blockIdx.x & 1;
    const size_t base = (size_t)b * L_ * N_;
    const int bL = b * L_;

    if (bw == 0) {
        // ================= FORWARD =================
        // path-score half: t in [1, TM)
        float pacc = 0.f;
        for (int t = 1 + l; t < TM; t += 64) {
            int cur  = tg[bL + t];
            int prev = tg[bL + t - 1];
            pacc += mask[bL + t] * (trans[prev * N_ + cur] + em[base + (size_t)t * N_ + cur]);
        }
        pacc = wave_sum(pacc);
        if (l == 0) {
            int t0 = tg[bL];
            pathf[b] = pacc + st[t0] + em[base + t0];
        }

#pragma unroll
        for (int k = 0; k < 4; ++k) Mlds[l + 64 * k] = mask[bL + l + 64 * k];

        // B-fragments: Bf[jt][ks][e] = exp(trans[32ks + 8h + e][16jt + c])
        h8_t Bf[8][4];
#pragma unroll
        for (int jt = 0; jt < 8; ++jt)
#pragma unroll
            for (int ks = 0; ks < 4; ++ks) {
                h8_t f;
#pragma unroll
                for (int e = 0; e < 8; ++e)
                    f[e] = (_Float16)__expf(trans[(32 * ks + 8 * h + e) * N_ + 16 * jt + c]);
                Bf[jt][ks] = f;
            }

        // init alpha_0
        float ns0 = st[s0] + em[base + s0];
        float ns1 = st[s1] + em[base + s1];
        float Mprev = wave_max(fmaxf(ns0, ns1));
        Eh[s0] = (_Float16)__expf(ns0 - Mprev - C_BIAS);
        Eh[s1] = (_Float16)__expf(ns1 - Mprev - C_BIAS);

        float pa0 = em[base + (size_t)1 * N_ + s0], pb0 = em[base + (size_t)1 * N_ + s1];
        float pa1 = em[base + (size_t)2 * N_ + s0], pb1 = em[base + (size_t)2 * N_ + s1];
        float pa2 = em[base + (size_t)3 * N_ + s0], pb2 = em[base + (size_t)3 * N_ + s1];
        float pa3 = em[base + (size_t)4 * N_ + s0], pb3 = em[base + (size_t)4 * N_ + s1];

        auto step = [&](int t, float& sa, float& sb) {
            float emv0 = sa, emv1 = sb;
            int tpf = t + 4; if (tpf > TM - 1) tpf = TM - 1;
            sa = em[base + (size_t)tpf * N_ + s0];
            sb = em[base + (size_t)tpf * N_ + s1];
            float mk = Mlds[t];

            float mx = wave_max(fmaxf(ns0, ns1));   // max(ns_{t-1}); overlaps MFMA

            // A-fragments: E[32ks + 8h + e] — row-uniform broadcast reads
            const _Float16* Eb = (const _Float16*)Eh;
            h8_t A0 = *(const h8_t*)(Eb + 8 * h);
            h8_t A1 = *(const h8_t*)(Eb + 32 + 8 * h);
            h8_t A2 = *(const h8_t*)(Eb + 64 + 8 * h);
            h8_t A3 = *(const h8_t*)(Eb + 96 + 8 * h);

            f4_t z = {0.f, 0.f, 0.f, 0.f};
            CHAIN4(q0, Bf[0]) CHAIN4(q1, Bf[1]) CHAIN4(q2, Bf[2]) CHAIN4(q3, Bf[3])
            CHAIN4(q4, Bf[4]) CHAIN4(q5, Bf[5]) CHAIN4(q6, Bf[6]) CHAIN4(q7, Bf[7])

            // in-register pickup of owned states (replicated D rows, reg 0)
            float sv0 = hb1 ? (hb0 ? q6[0] : q4[0]) : (hb0 ? q2[0] : q0[0]);
            float sv1 = hb1 ? (hb0 ? q7[0] : q5[0]) : (hb0 ? q3[0] : q1[0]);

            float badd = Mprev + C_BIAS;
            float nxt0 = __logf(sv0) + badd + emv0;
            float nxt1 = __logf(sv1) + badd + emv1;
            float im = 1.f - mk;
            ns0 = mk * nxt0 + im * ns0;
            ns1 = mk * nxt1 + im * ns1;

            Mprev = mx;
            Eh[s0] = (_Float16)__expf(ns0 - mx - C_BIAS);
            Eh[s1] = (_Float16)__expf(ns1 - mx - C_BIAS);
        };

        for (int tt = 1; tt + 3 < TM; tt += 4) {
            step(tt    , pa0, pb0);
            step(tt + 1, pa1, pb1);
            step(tt + 2, pa2, pb2);
            step(tt + 3, pa3, pb3);
        }
        step(TM - 3, pa0, pb0);
        step(TM - 2, pa1, pb1);
        step(TM - 1, pa2, pb2);

        alpha[b * N_ + s0] = ns0;
        alpha[b * N_ + s1] = ns1;
    } else {
        // ================= BACKWARD =================
        // path-score half: t in [TM, L)
        float pacc = 0.f;
        for (int t = TM + l; t < L_; t += 64) {
            int cur  = tg[bL + t];
            int prev = tg[bL + t - 1];
            pacc += mask[bL + t] * (trans[prev * N_ + cur] + em[base + (size_t)t * N_ + cur]);
        }
        pacc = wave_sum(pacc);
        if (l == 0) pathb[b] = pacc;

#pragma unroll
        for (int k = 0; k < 4; ++k) Mlds[l + 64 * k] = mask[bL + TM + l + 64 * k];

        // B-fragments: Bf[it][ks][e] = exp(trans[16it + c][32ks + 8h + e])
        h8_t Bf[8][4];
#pragma unroll
        for (int it = 0; it < 8; ++it)
#pragma unroll
            for (int ks = 0; ks < 4; ++ks) {
                const float* p = trans + (size_t)(16 * it + c) * N_ + 32 * ks + 8 * h;
                float4 q0 = *(const float4*)p;
                float4 q1 = *(const float4*)(p + 4);
                h8_t f;
                f[0] = (_Float16)__expf(q0.x); f[1] = (_Float16)__expf(q0.y);
                f[2] = (_Float16)__expf(q0.z); f[3] = (_Float16)__expf(q0.w);
                f[4] = (_Float16)__expf(q1.x); f[5] = (_Float16)__expf(q1.y);
                f[6] = (_Float16)__expf(q1.z); f[7] = (_Float16)__expf(q1.w);
                Bf[it][ks] = f;
            }

        // init at u=511: beta_511 = 0 ; v = beta + em_511
        float b0 = 0.f, b1 = 0.f;
        float v0 = em[base + (size_t)(L_ - 1) * N_ + s0];
        float v1 = em[base + (size_t)(L_ - 1) * N_ + s1];
        float Mprev = wave_max(fmaxf(v0, v1));
        Eh[s0] = (_Float16)__expf(v0 - Mprev - C_BIAS);
        Eh[s1] = (_Float16)__expf(v1 - Mprev - C_BIAS);

        float pa0 = em[base + (size_t)510 * N_ + s0], pb0 = em[base + (size_t)510 * N_ + s1];
        float pa1 = em[base + (size_t)509 * N_ + s0], pb1 = em[base + (size_t)509 * N_ + s1];
        float pa2 = em[base + (size_t)508 * N_ + s0], pb2 = em[base + (size_t)508 * N_ + s1];
        float pa3 = em[base + (size_t)507 * N_ + s0], pb3 = em[base + (size_t)507 * N_ + s1];

        // iter t (510 down to 255): consumes F_{t+1} (Eh), em_t (pipe), mask_{t+1}
        auto step = [&](int t, float& sa, float& sb) {
            float emt0 = sa, emt1 = sb;
            int tpf = t - 4; if (tpf < TM - 1) tpf = TM - 1;
            sa = em[base + (size_t)tpf * N_ + s0];
            sb = em[base + (size_t)tpf * N_ + s1];
            float mk = Mlds[t + 1 - TM];

            float mx = wave_max(fmaxf(v0, v1));   // max(v_{t+1}); overlaps MFMA

            const _Float16* Fb = (const _Float16*)Eh;
            h8_t A0 = *(const h8_t*)(Fb + 8 * h);
            h8_t A1 = *(const h8_t*)(Fb + 32 + 8 * h);
            h8_t A2 = *(const h8_t*)(Fb + 64 + 8 * h);
            h8_t A3 = *(const h8_t*)(Fb + 96 + 8 * h);

            f4_t z = {0.f, 0.f, 0.f, 0.f};
            CHAIN4(q0, Bf[0]) CHAIN4(q1, Bf[1]) CHAIN4(q2, Bf[2]) CHAIN4(q3, Bf[3])
            CHAIN4(q4, Bf[4]) CHAIN4(q5, Bf[5]) CHAIN4(q6, Bf[6]) CHAIN4(q7, Bf[7])

            float sv0 = hb1 ? (hb0 ? q6[0] : q4[0]) : (hb0 ? q2[0] : q0[0]);
            float sv1 = hb1 ? (hb0 ? q7[0] : q5[0]) : (hb0 ? q3[0] : q1[0]);

            float badd = Mprev + C_BIAS;
            float upd0 = __logf(sv0) + badd;
            float upd1 = __logf(sv1) + badd;
            float im = 1.f - mk;
            b0 = mk * upd0 + im * b0;
            b1 = mk * upd1 + im * b1;

            v0 = b0 + emt0;
            v1 = b1 + emt1;
            Mprev = mx;
            Eh[s0] = (_Float16)__expf(v0 - mx - C_BIAS);
            Eh[s1] = (_Float16)__expf(v1 - mx - C_BIAS);
        };

        for (int tt = 510; tt >= 258; tt -= 4) {   // 64 groups x 4 = t 510..255
            step(tt    , pa0, pb0);
            step(tt - 1, pa1, pb1);
            step(tt - 2, pa2, pb2);
            step(tt - 3, pa3, pb3);
        }

        beta[b * N_ + s0] = b0;
        beta[b * N_ + s1] = b1;
    }
}

// ---------------------------------------------------------------------------
// zres_kernel: 512 blocks x 1 wave. Block b: zres[b] = LSE_j(alpha[j]+beta[j])
//              - pathf[b] - pathb[b].
// ---------------------------------------------------------------------------
__global__ __launch_bounds__(64) void zres_kernel(
    const float* __restrict__ alpha, const float* __restrict__ beta,
    const float* __restrict__ pathf, const float* __restrict__ pathb,
    float* __restrict__ zres)
{
    const int l = threadIdx.x;
    const int b = blockIdx.x;
    float2 av = *(const float2*)(alpha + b * N_ + 2 * l);
    float2 bv = *(const float2*)(beta  + b * N_ + 2 * l);
    float v0 = av.x + bv.x;
    float v1 = av.y + bv.y;
    float m = wave_max(fmaxf(v0, v1));
    float s = wave_sum(__expf(v0 - m) + __expf(v1 - m));
    if (l == 0) zres[b] = m + __logf(s) - pathf[b] - pathb[b];
}

// ---------------------------------------------------------------------------
// mean_kernel: 1 wave. out = mean(zres). 8 values/lane (2x float4) + DPP tree.
// ---------------------------------------------------------------------------
__global__ __launch_bounds__(64) void mean_kernel(
    const float* __restrict__ zres, float* __restrict__ out)
{
    const int l = threadIdx.x;
    const float4* z4 = (const float4*)zres;
    float4 a = z4[2 * l];
    float4 c = z4[2 * l + 1];
    float acc = ((a.x + a.y) + (a.z + a.w)) + ((c.x + c.y) + (c.z + c.w));
    acc = wave_sum(acc);
    if (l == 0) out[0] = acc * (1.0f / (float)B_);
}

// ---------------------------------------------------------------------------
extern "C" void kernel_launch(void* const* d_in, const int* in_sizes, int n_in,
                              void* d_out, int out_size, void* d_ws, size_t ws_size,
                              hipStream_t stream) {
    const float* emission    = (const float*)d_in[0];
    const int*   target      = (const int*)  d_in[1];
    const float* mask        = (const float*)d_in[2];
    const float* start_trans = (const float*)d_in[3];
    const float* trans       = (const float*)d_in[4];
    float* out = (float*)d_out;

    float* ws_f  = (float*)d_ws;
    float* alpha = ws_f;                        // 512*128
    float* beta  = ws_f + B_ * N_;              // 512*128
    float* pathf = ws_f + 2 * B_ * N_;          // 512
    float* pathb = ws_f + 2 * B_ * N_ + B_;     // 512
    float* zres  = ws_f + 2 * B_ * N_ + 2 * B_; // 512

    norm_kernel<<<2 * B_, 64, 0, stream>>>(emission, target, mask, start_trans,
                                           trans, alpha, beta, pathf, pathb);
    zres_kernel<<<B_, 64, 0, stream>>>(alpha, beta, pathf, pathb, zres);
    mean_kernel<<<1, 64, 0, stream>>>(zres, out);
}